// Round 1
// baseline (380.870 us; speedup 1.0000x reference)
//
#include <hip/hip_runtime.h>

// out[b,t] = sum_d x[b,t,d] * stimulus[b,t,d]
// B=8, T=8192, D=768  -> 65536 rows of 768 fp32 each.
// One 64-lane wave per row: 3 float4 loads/lane/input (192 float4 per row),
// per-lane FMA, then shfl wave reduction. Pure HBM-bound streaming.

constexpr int D = 768;
constexpr int D4 = D / 4;          // 192 float4 per row
constexpr int ROWS = 8 * 8192;     // 65536

__global__ __launch_bounds__(256) void row_dot_kernel(
    const float4* __restrict__ x,
    const float4* __restrict__ s,
    float* __restrict__ out)
{
    const int wave = (blockIdx.x * blockDim.x + threadIdx.x) >> 6;
    const int lane = threadIdx.x & 63;
    if (wave >= ROWS) return;

    const size_t base = (size_t)wave * D4;

    float acc = 0.0f;
#pragma unroll
    for (int c = 0; c < 3; ++c) {
        float4 a = x[base + c * 64 + lane];
        float4 b = s[base + c * 64 + lane];
        acc = fmaf(a.x, b.x, acc);
        acc = fmaf(a.y, b.y, acc);
        acc = fmaf(a.z, b.z, acc);
        acc = fmaf(a.w, b.w, acc);
    }

    // 64-lane wave reduction
#pragma unroll
    for (int off = 32; off > 0; off >>= 1)
        acc += __shfl_down(acc, off, 64);

    if (lane == 0) out[wave] = acc;
}

extern "C" void kernel_launch(void* const* d_in, const int* in_sizes, int n_in,
                              void* d_out, int out_size, void* d_ws, size_t ws_size,
                              hipStream_t stream)
{
    const float4* x = (const float4*)d_in[0];
    const float4* s = (const float4*)d_in[1];
    float* out = (float*)d_out;

    // 4 waves (256 threads) per block, one wave per row.
    const int waves_per_block = 4;
    const int blocks = ROWS / waves_per_block;   // 16384
    row_dot_kernel<<<blocks, 256, 0, stream>>>(x, s, out);
}